// Round 5
// baseline (1389.661 us; speedup 1.0000x reference)
//
#include <hip/hip_runtime.h>
#include <math.h>

// ---------------------------------------------------------------------------
// Dense: out[M,128] = A[M,K] @ W[K,128] (+ bias). W staged in LDS.
// block = 256 threads; each block does 64 rows; micro-tile 8 rows x 4 cols.
// ---------------------------------------------------------------------------
template<int K, bool HAS_BIAS>
__global__ __launch_bounds__(256) void dense_k(
    const float* __restrict__ A, const float* __restrict__ W,
    const float* __restrict__ bias, float* __restrict__ out, int M)
{
    __shared__ float Wl[K * 128];
    const int t = threadIdx.x;
    for (int idx = t * 4; idx < K * 128; idx += 1024)
        *(float4*)&Wl[idx] = *(const float4*)&W[idx];
    __syncthreads();

    const int tx = t & 31, ty = t >> 5;
    const int c0 = tx * 4;
    const long row0 = (long)blockIdx.x * 64 + (long)ty * 8;

    const float* Ap[8];
#pragma unroll
    for (int i = 0; i < 8; i++) {
        long r = row0 + i; if (r > (long)M - 1) r = (long)M - 1;
        Ap[i] = A + r * K;
    }
    float4 acc[8];
#pragma unroll
    for (int i = 0; i < 8; i++) acc[i] = make_float4(0.f, 0.f, 0.f, 0.f);

    for (int k = 0; k < K; k += 4) {
        const float4 w0 = *(const float4*)&Wl[(k + 0) * 128 + c0];
        const float4 w1 = *(const float4*)&Wl[(k + 1) * 128 + c0];
        const float4 w2 = *(const float4*)&Wl[(k + 2) * 128 + c0];
        const float4 w3 = *(const float4*)&Wl[(k + 3) * 128 + c0];
#pragma unroll
        for (int i = 0; i < 8; i++) {
            const float4 a = *(const float4*)(Ap[i] + k);
            acc[i].x += a.x * w0.x + a.y * w1.x + a.z * w2.x + a.w * w3.x;
            acc[i].y += a.x * w0.y + a.y * w1.y + a.z * w2.y + a.w * w3.y;
            acc[i].z += a.x * w0.z + a.y * w1.z + a.z * w2.z + a.w * w3.z;
            acc[i].w += a.x * w0.w + a.y * w1.w + a.z * w2.w + a.w * w3.w;
        }
    }
    float4 bv = make_float4(0.f, 0.f, 0.f, 0.f);
    if (HAS_BIAS) bv = *(const float4*)&bias[c0];
#pragma unroll
    for (int i = 0; i < 8; i++) {
        long r = row0 + i;
        if (r < M) {
            float4 o;
            o.x = acc[i].x + bv.x; o.y = acc[i].y + bv.y;
            o.z = acc[i].z + bv.z; o.w = acc[i].w + bv.w;
            *(float4*)&out[r * 128 + c0] = o;
        }
    }
}

// ---------------------------------------------------------------------------
// Degree count (real edges only; self-loop added analytically later)
// ---------------------------------------------------------------------------
__global__ void count_edges_k(const int* __restrict__ dst, int* __restrict__ cnt, int E)
{
    int e = blockIdx.x * 256 + threadIdx.x;
    if (e < E) atomicAdd(&cnt[dst[e]], 1);
}

__global__ void dinv_k(const int* __restrict__ cnt, float* __restrict__ dinv, int N)
{
    int i = blockIdx.x * 256 + threadIdx.x;
    if (i < N) dinv[i] = rsqrtf((float)cnt[i] + 1.0f);   // +1 = self loop
}

// ---------------------------------------------------------------------------
// 3-kernel exclusive prefix scan over cnt -> offs
// ---------------------------------------------------------------------------
__global__ void scan_block_k(const int* __restrict__ cnt, int* __restrict__ offs,
                             int* __restrict__ bsums, int N)
{
    __shared__ int tmp[256];
    int i = blockIdx.x * 256 + threadIdx.x;
    int v = (i < N) ? cnt[i] : 0;
    tmp[threadIdx.x] = v;
    __syncthreads();
    for (int off = 1; off < 256; off <<= 1) {
        int add = (threadIdx.x >= off) ? tmp[threadIdx.x - off] : 0;
        __syncthreads();
        tmp[threadIdx.x] += add;
        __syncthreads();
    }
    if (i < N) offs[i] = tmp[threadIdx.x] - v;           // exclusive within block
    if (threadIdx.x == 255) bsums[blockIdx.x] = tmp[255];
}

__global__ void scan_tops_k(int* __restrict__ bsums, int nb)
{
    __shared__ int tmp[512];
    int t = threadIdx.x;
    int v = (t < nb) ? bsums[t] : 0;
    tmp[t] = v;
    __syncthreads();
    for (int off = 1; off < 512; off <<= 1) {
        int add = (t >= off) ? tmp[t - off] : 0;
        __syncthreads();
        tmp[t] += add;
        __syncthreads();
    }
    if (t < nb) bsums[t] = tmp[t] - v;                   // exclusive over blocks
}

__global__ void scan_add_k(int* __restrict__ offs, const int* __restrict__ bsums,
                           int N, int E)
{
    int i = blockIdx.x * 256 + threadIdx.x;
    if (i < N) offs[i] += bsums[blockIdx.x];
    if (i == 0) offs[N] = E;
}

// ---------------------------------------------------------------------------
// CSR fill: interleaved (src, norm) pairs grouped by dst, packed in 64 bits
// ---------------------------------------------------------------------------
__global__ void fill_csr_k(const int* __restrict__ src, const int* __restrict__ dst,
                           const int* __restrict__ offs, int* __restrict__ fillc,
                           const float* __restrict__ dinv,
                           unsigned long long* __restrict__ csr, int E)
{
    int e = blockIdx.x * 256 + threadIdx.x;
    if (e >= E) return;
    int s = src[e], d = dst[e];
    int slot = offs[d] + atomicAdd(&fillc[d], 1);
    unsigned long long p = (unsigned long long)(unsigned)s |
        ((unsigned long long)(unsigned)__float_as_uint(dinv[s] * dinv[d]) << 32);
    csr[slot] = p;
}

// ---------------------------------------------------------------------------
// Aggregation: one wave per node, lane handles 2 features (float2).
// 8 independent 512B gathers in flight per wave; clamp-predicated tail
// (no serial remainder loop). csr stream loaded non-temporally (scalar u64).
// ---------------------------------------------------------------------------
__global__ __launch_bounds__(256) void aggregate_k(
    const float* __restrict__ hw, const int* __restrict__ offs,
    const unsigned long long* __restrict__ csr, const float* __restrict__ dinv,
    const float* __restrict__ bconv, float* __restrict__ hout, int N)
{
    const int wid = threadIdx.x >> 6;
    const int lane = threadIdx.x & 63;
    const long node = (long)blockIdx.x * 4 + wid;
    if (node >= N) return;
    const int f = lane * 2;

    const float di = dinv[node];
    float2 self = *(const float2*)&hw[node * 128 + f];
    float2 acc;
    acc.x = self.x * di * di;
    acc.y = self.y * di * di;

    const int beg = offs[node];
    const int end = offs[node + 1];

    if (end > beg) {
        const int endc = end - 1;
        for (int k = beg; k < end; k += 8) {
            unsigned long long e[8];
#pragma unroll
            for (int j = 0; j < 8; j++) {
                int kk = k + j;
                kk = (kk <= endc) ? kk : endc;
                e[j] = __builtin_nontemporal_load(&csr[kk]);
            }
            float w[8];
#pragma unroll
            for (int j = 0; j < 8; j++)
                w[j] = (k + j < end) ? __uint_as_float((unsigned)(e[j] >> 32)) : 0.0f;

            float2 v[8];
#pragma unroll
            for (int j = 0; j < 8; j++) {
                const long s = (long)(unsigned)(e[j] & 0xffffffffu);
                v[j] = *(const float2*)&hw[s * 128 + f];
            }
#pragma unroll
            for (int j = 0; j < 8; j++) {
                acc.x += v[j].x * w[j];
                acc.y += v[j].y * w[j];
            }
        }
    }

    const float2 b = *(const float2*)&bconv[f];
    float2 o;
    o.x = tanhf(acc.x + b.x);
    o.y = tanhf(acc.y + b.y);
    *(float2*)&hout[node * 128 + f] = o;
}

// ---------------------------------------------------------------------------
// Graph ranges from sorted batch
// ---------------------------------------------------------------------------
__global__ void graph_bounds_k(const int* __restrict__ batch, int* __restrict__ goffs,
                               int N, int G)
{
    int i = blockIdx.x * 256 + threadIdx.x;
    if (i >= N) return;
    int b = batch[i];
    int prev = (i == 0) ? -1 : batch[i - 1];
    for (int g = prev + 1; g <= b; g++) goffs[g] = i;
    if (i == N - 1)
        for (int g = b + 1; g <= G; g++) goffs[g] = N;
}

// ---------------------------------------------------------------------------
// Pool stage 1: parallel partial reduction over node chunks.
// ---------------------------------------------------------------------------
__device__ __forceinline__ unsigned enc_f32(float x)
{
    unsigned u = __float_as_uint(x);
    return (u & 0x80000000u) ? ~u : (u | 0x80000000u);
}
__device__ __forceinline__ float dec_f32(unsigned u)
{
    return (u & 0x80000000u) ? __uint_as_float(u ^ 0x80000000u)
                             : __uint_as_float(~u);
}

#define POOL_CHUNK 32

__global__ __launch_bounds__(128) void pool_partial_k(
    const float* __restrict__ h, const int* __restrict__ batch,
    float* __restrict__ sums, unsigned* __restrict__ maxu, int N)
{
    const int t = threadIdx.x;
    const int lane = t & 31;          // feature group: 4 floats
    const int sub = t >> 5;           // row offset within 4-row sweep
    const int f4 = lane * 4;
    const int i0 = blockIdx.x * POOL_CHUNK;
    const int i1 = min(i0 + POOL_CHUNK, N);

    int cur = -1;
    float4 s = make_float4(0.f, 0.f, 0.f, 0.f);
    float4 m = make_float4(-INFINITY, -INFINITY, -INFINITY, -INFINITY);

#pragma unroll 4
    for (int i = i0 + sub; i < i1; i += 4) {
        const int b = batch[i];
        const float4 v = *(const float4*)&h[(long)i * 128 + f4];
        if (b != cur) {
            if (cur >= 0) {
                atomicAdd(&sums[cur * 128 + f4 + 0], s.x);
                atomicAdd(&sums[cur * 128 + f4 + 1], s.y);
                atomicAdd(&sums[cur * 128 + f4 + 2], s.z);
                atomicAdd(&sums[cur * 128 + f4 + 3], s.w);
                atomicMax(&maxu[cur * 128 + f4 + 0], enc_f32(m.x));
                atomicMax(&maxu[cur * 128 + f4 + 1], enc_f32(m.y));
                atomicMax(&maxu[cur * 128 + f4 + 2], enc_f32(m.z));
                atomicMax(&maxu[cur * 128 + f4 + 3], enc_f32(m.w));
            }
            s = make_float4(0.f, 0.f, 0.f, 0.f);
            m = make_float4(-INFINITY, -INFINITY, -INFINITY, -INFINITY);
            cur = b;
        }
        s.x += v.x; s.y += v.y; s.z += v.z; s.w += v.w;
        m.x = fmaxf(m.x, v.x); m.y = fmaxf(m.y, v.y);
        m.z = fmaxf(m.z, v.z); m.w = fmaxf(m.w, v.w);
    }
    if (cur >= 0) {
        atomicAdd(&sums[cur * 128 + f4 + 0], s.x);
        atomicAdd(&sums[cur * 128 + f4 + 1], s.y);
        atomicAdd(&sums[cur * 128 + f4 + 2], s.z);
        atomicAdd(&sums[cur * 128 + f4 + 3], s.w);
        atomicMax(&maxu[cur * 128 + f4 + 0], enc_f32(m.x));
        atomicMax(&maxu[cur * 128 + f4 + 1], enc_f32(m.y));
        atomicMax(&maxu[cur * 128 + f4 + 2], enc_f32(m.z));
        atomicMax(&maxu[cur * 128 + f4 + 3], enc_f32(m.w));
    }
}

// ---------------------------------------------------------------------------
// Pool stage 2: finalize [sum | max | mean] per graph
// ---------------------------------------------------------------------------
__global__ __launch_bounds__(128) void pool_final_k(
    const float* __restrict__ sums, const unsigned* __restrict__ maxu,
    const int* __restrict__ goffs, float* __restrict__ gout)
{
    const int g = blockIdx.x, f = threadIdx.x;
    const int cnt = goffs[g + 1] - goffs[g];
    const float s = sums[g * 128 + f];
    float mx = (cnt > 0) ? dec_f32(maxu[g * 128 + f]) : 0.0f;
    if (!isfinite(mx)) mx = 0.0f;
    const float mean = s / fmaxf((float)cnt, 1.0f);
    gout[g * 384 + f]       = s;
    gout[g * 384 + 128 + f] = mx;
    gout[g * 384 + 256 + f] = mean;
}

// ---------------------------------------------------------------------------
// MLP head: one block per graph
// ---------------------------------------------------------------------------
__global__ __launch_bounds__(192) void mlp_k(const float* __restrict__ gbuf,
                                             const float* __restrict__ W1,
                                             const float* __restrict__ b1,
                                             const float* __restrict__ W2,
                                             const float* __restrict__ b2,
                                             float* __restrict__ out)
{
    __shared__ float gr[384];
    __shared__ float g1[192];
    const int g = blockIdx.x, t = threadIdx.x;
    for (int i = t; i < 384; i += 192) gr[i] = gbuf[g * 384 + i];
    __syncthreads();
    float acc = b1[t];
    for (int k = 0; k < 384; k++) acc += gr[k] * W1[k * 192 + t];
    acc = acc > 0.f ? acc : 0.01f * acc;
    g1[t] = acc;
    __syncthreads();
    if (t < 10) {
        float a = b2[t];
        for (int k = 0; k < 192; k++) a += g1[k] * W2[k * 10 + t];
        a = a > 0.f ? a : 0.01f * a;
        out[g * 10 + t] = a;
    }
}

// ---------------------------------------------------------------------------
extern "C" void kernel_launch(void* const* d_in, const int* in_sizes, int n_in,
                              void* d_out, int out_size, void* d_ws, size_t ws_size,
                              hipStream_t stream)
{
    const float* x      = (const float*)d_in[0];
    const int*   ei     = (const int*)d_in[1];
    const int*   batch  = (const int*)d_in[2];
    const float* W_emb  = (const float*)d_in[3];
    const float* b_emb  = (const float*)d_in[4];
    const float* W_conv = (const float*)d_in[5];
    const float* b_conv = (const float*)d_in[6];
    const float* W1     = (const float*)d_in[7];
    const float* b1     = (const float*)d_in[8];
    const float* W2     = (const float*)d_in[9];
    const float* b2     = (const float*)d_in[10];
    float* out = (float*)d_out;

    const int N  = in_sizes[2];          // 100000
    const int E  = in_sizes[1] / 2;      // 1600000
    const int G  = 128;
    const int NL = 5;
    const int HID = 128;

    const int* e_src = ei;
    const int* e_dst = ei + E;

    // workspace carve-up
    char* ws = (char*)d_ws;
    size_t off = 0;
    auto alloc = [&](size_t bytes) -> void* {
        void* p = ws + off;
        off += (bytes + 255) & ~(size_t)255;
        return p;
    };
    float*    hbuf     = (float*)   alloc((size_t)N * HID * 4);
    float*    hwbuf    = (float*)   alloc((size_t)N * HID * 4);
    float*    dinv     = (float*)   alloc((size_t)N * 4);
    int*      cnt      = (int*)     alloc((size_t)N * 4);
    int*      offs     = (int*)     alloc((size_t)(N + 1) * 4);
    int*      bsums    = (int*)     alloc(512 * 4);
    unsigned long long* csr = (unsigned long long*)alloc((size_t)E * 8);
    int*      goffs    = (int*)     alloc((size_t)(G + 1) * 4);
    float*    gbuf     = (float*)   alloc((size_t)G * 384 * 4);
    float*    psums    = (float*)   alloc((size_t)G * 128 * 4);
    unsigned* pmaxu    = (unsigned*)alloc((size_t)G * 128 * 4);

    const int nb_nodes = (N + 255) / 256;
    const int nb_edges = (E + 255) / 256;

    // 1) degree + dinv
    (void)hipMemsetAsync(cnt, 0, (size_t)N * 4, stream);
    count_edges_k<<<nb_edges, 256, 0, stream>>>(e_dst, cnt, E);
    dinv_k<<<nb_nodes, 256, 0, stream>>>(cnt, dinv, N);

    // 2) CSR offsets (exclusive scan of cnt)
    scan_block_k<<<nb_nodes, 256, 0, stream>>>(cnt, offs, bsums, N);
    scan_tops_k<<<1, 512, 0, stream>>>(bsums, nb_nodes);
    scan_add_k<<<nb_nodes, 256, 0, stream>>>(offs, bsums, N, E);

    // 3) CSR fill
    (void)hipMemsetAsync(cnt, 0, (size_t)N * 4, stream);
    fill_csr_k<<<nb_edges, 256, 0, stream>>>(e_src, e_dst, offs, cnt, dinv, csr, E);

    // 4) input embedding: h = x @ W_emb + b_emb
    dense_k<64, true><<<(N + 63) / 64, 256, 0, stream>>>(x, W_emb, b_emb, hbuf, N);

    // 5) GCN layers
    for (int l = 0; l < NL; l++) {
        dense_k<128, false><<<(N + 63) / 64, 256, 0, stream>>>(
            hbuf, W_conv + (size_t)l * HID * HID, nullptr, hwbuf, N);
        aggregate_k<<<(N + 3) / 4, 256, 0, stream>>>(
            hwbuf, offs, csr, dinv, b_conv + (size_t)l * HID, hbuf, N);
    }

    // 6) pooling (parallel two-stage)
    graph_bounds_k<<<nb_nodes, 256, 0, stream>>>(batch, goffs, N, G);
    (void)hipMemsetAsync(psums, 0, (size_t)G * 128 * 4, stream);
    (void)hipMemsetAsync(pmaxu, 0, (size_t)G * 128 * 4, stream);
    pool_partial_k<<<(N + POOL_CHUNK - 1) / POOL_CHUNK, 128, 0, stream>>>(
        hbuf, batch, psums, pmaxu, N);
    pool_final_k<<<G, 128, 0, stream>>>(psums, pmaxu, goffs, gbuf);

    // 7) MLP head
    mlp_k<<<G, 192, 0, stream>>>(gbuf, W1, b1, W2, b2, out);
}

// Round 6
// 1133.536 us; speedup vs baseline: 1.2260x; 1.2260x over previous
//
#include <hip/hip_runtime.h>
#include <math.h>

// ---------------------------------------------------------------------------
// Dense v2: out[M,128] = A[M,K] @ W[K,128] (+ bias).
// 128x128 block tile, BK=32 k-chunks, A and W staged in LDS, 8x8 micro-tile.
// 256 threads = 16x16; thread (ty,tx) owns rows ty*8..+7, cols tx*8..+7.
// ---------------------------------------------------------------------------
template<int K, bool HAS_BIAS>
__global__ __launch_bounds__(256) void dense_k(
    const float* __restrict__ A, const float* __restrict__ W,
    const float* __restrict__ bias, float* __restrict__ out, int M)
{
    constexpr int BK = 32;
    __shared__ float As[128 * BK];   // row-major [128][BK]
    __shared__ float Ws[BK * 128];   // row-major [BK][128]

    const int t  = threadIdx.x;
    const int tx = t & 15, ty = t >> 4;
    const int c0 = tx * 8;
    const int r0 = ty * 8;
    const long row0 = (long)blockIdx.x * 128;

    float acc[8][8] = {{0.f}};

    for (int k0 = 0; k0 < K; k0 += BK) {
        // stage A tile: 128 rows x BK floats = 1024 float4, linear across threads
#pragma unroll
        for (int it = 0; it < 4; it++) {
            const int f  = t + it * 256;      // float4 index 0..1023
            const int r  = f >> 3;            // 8 float4 per row
            const int kq = f & 7;
            long gr = row0 + r; if (gr > (long)M - 1) gr = (long)M - 1;
            *(float4*)&As[r * BK + kq * 4] =
                *(const float4*)&A[gr * K + k0 + kq * 4];
        }
        // stage W tile: BK x 128 = 1024 float4, pure linear copy
#pragma unroll
        for (int it = 0; it < 4; it++) {
            const int f = t + it * 256;
            *(float4*)&Ws[f * 4] = *(const float4*)&W[(long)k0 * 128 + f * 4];
        }
        __syncthreads();

#pragma unroll
        for (int kq = 0; kq < BK / 4; kq++) {
            float4 a[8];
#pragma unroll
            for (int i = 0; i < 8; i++)
                a[i] = *(const float4*)&As[(r0 + i) * BK + kq * 4];
#pragma unroll
            for (int kk = 0; kk < 4; kk++) {
                const int k = kq * 4 + kk;
                const float4 w0 = *(const float4*)&Ws[k * 128 + c0];
                const float4 w1 = *(const float4*)&Ws[k * 128 + c0 + 4];
#pragma unroll
                for (int i = 0; i < 8; i++) {
                    const float av = (kk == 0) ? a[i].x : (kk == 1) ? a[i].y
                                   : (kk == 2) ? a[i].z : a[i].w;
                    acc[i][0] += av * w0.x; acc[i][1] += av * w0.y;
                    acc[i][2] += av * w0.z; acc[i][3] += av * w0.w;
                    acc[i][4] += av * w1.x; acc[i][5] += av * w1.y;
                    acc[i][6] += av * w1.z; acc[i][7] += av * w1.w;
                }
            }
        }
        __syncthreads();
    }

    float4 b0 = make_float4(0.f, 0.f, 0.f, 0.f);
    float4 b1 = make_float4(0.f, 0.f, 0.f, 0.f);
    if (HAS_BIAS) {
        b0 = *(const float4*)&bias[c0];
        b1 = *(const float4*)&bias[c0 + 4];
    }
#pragma unroll
    for (int i = 0; i < 8; i++) {
        const long gr = row0 + r0 + i;
        if (gr < M) {
            float4 o0, o1;
            o0.x = acc[i][0] + b0.x; o0.y = acc[i][1] + b0.y;
            o0.z = acc[i][2] + b0.z; o0.w = acc[i][3] + b0.w;
            o1.x = acc[i][4] + b1.x; o1.y = acc[i][5] + b1.y;
            o1.z = acc[i][6] + b1.z; o1.w = acc[i][7] + b1.w;
            *(float4*)&out[gr * 128 + c0]     = o0;
            *(float4*)&out[gr * 128 + c0 + 4] = o1;
        }
    }
}

// ---------------------------------------------------------------------------
// Degree count (real edges only; self-loop added analytically later)
// ---------------------------------------------------------------------------
__global__ void count_edges_k(const int* __restrict__ dst, int* __restrict__ cnt, int E)
{
    int e = blockIdx.x * 256 + threadIdx.x;
    if (e < E) atomicAdd(&cnt[dst[e]], 1);
}

__global__ void dinv_k(const int* __restrict__ cnt, float* __restrict__ dinv, int N)
{
    int i = blockIdx.x * 256 + threadIdx.x;
    if (i < N) dinv[i] = rsqrtf((float)cnt[i] + 1.0f);   // +1 = self loop
}

// ---------------------------------------------------------------------------
// 3-kernel exclusive prefix scan over cnt -> offs
// ---------------------------------------------------------------------------
__global__ void scan_block_k(const int* __restrict__ cnt, int* __restrict__ offs,
                             int* __restrict__ bsums, int N)
{
    __shared__ int tmp[256];
    int i = blockIdx.x * 256 + threadIdx.x;
    int v = (i < N) ? cnt[i] : 0;
    tmp[threadIdx.x] = v;
    __syncthreads();
    for (int off = 1; off < 256; off <<= 1) {
        int add = (threadIdx.x >= off) ? tmp[threadIdx.x - off] : 0;
        __syncthreads();
        tmp[threadIdx.x] += add;
        __syncthreads();
    }
    if (i < N) offs[i] = tmp[threadIdx.x] - v;           // exclusive within block
    if (threadIdx.x == 255) bsums[blockIdx.x] = tmp[255];
}

__global__ void scan_tops_k(int* __restrict__ bsums, int nb)
{
    __shared__ int tmp[512];
    int t = threadIdx.x;
    int v = (t < nb) ? bsums[t] : 0;
    tmp[t] = v;
    __syncthreads();
    for (int off = 1; off < 512; off <<= 1) {
        int add = (t >= off) ? tmp[t - off] : 0;
        __syncthreads();
        tmp[t] += add;
        __syncthreads();
    }
    if (t < nb) bsums[t] = tmp[t] - v;                   // exclusive over blocks
}

__global__ void scan_add_k(int* __restrict__ offs, const int* __restrict__ bsums,
                           int N, int E)
{
    int i = blockIdx.x * 256 + threadIdx.x;
    if (i < N) offs[i] += bsums[blockIdx.x];
    if (i == 0) offs[N] = E;
}

// ---------------------------------------------------------------------------
// CSR fill: interleaved (src, norm) pairs grouped by dst
// ---------------------------------------------------------------------------
__global__ void fill_csr_k(const int* __restrict__ src, const int* __restrict__ dst,
                           const int* __restrict__ offs, int* __restrict__ fillc,
                           const float* __restrict__ dinv,
                           int2* __restrict__ csr, int E)
{
    int e = blockIdx.x * 256 + threadIdx.x;
    if (e >= E) return;
    int s = src[e], d = dst[e];
    int slot = offs[d] + atomicAdd(&fillc[d], 1);
    int2 p;
    p.x = s;
    p.y = __float_as_int(dinv[s] * dinv[d]);
    csr[slot] = p;
}

// ---------------------------------------------------------------------------
// Aggregation (R3 proven version): one wave per node, lane = 2 features.
// Edge loop unrolled x4 -> 4 independent 512B gathers in flight per wave.
// ---------------------------------------------------------------------------
__global__ __launch_bounds__(256) void aggregate_k(
    const float* __restrict__ hw, const int* __restrict__ offs,
    const int2* __restrict__ csr, const float* __restrict__ dinv,
    const float* __restrict__ bconv, float* __restrict__ hout, int N)
{
    const int wid = threadIdx.x >> 6;
    const int lane = threadIdx.x & 63;
    const long node = (long)blockIdx.x * 4 + wid;
    if (node >= N) return;
    const int f = lane * 2;

    const float di = dinv[node];
    float2 self = *(const float2*)&hw[node * 128 + f];
    float2 acc;
    acc.x = self.x * di * di;
    acc.y = self.y * di * di;

    int k = offs[node];
    const int end = offs[node + 1];

    while (k + 4 <= end) {
        const int2 e0 = csr[k + 0];
        const int2 e1 = csr[k + 1];
        const int2 e2 = csr[k + 2];
        const int2 e3 = csr[k + 3];
        const float2 v0 = *(const float2*)&hw[(long)e0.x * 128 + f];
        const float2 v1 = *(const float2*)&hw[(long)e1.x * 128 + f];
        const float2 v2 = *(const float2*)&hw[(long)e2.x * 128 + f];
        const float2 v3 = *(const float2*)&hw[(long)e3.x * 128 + f];
        const float w0 = __int_as_float(e0.y);
        const float w1 = __int_as_float(e1.y);
        const float w2 = __int_as_float(e2.y);
        const float w3 = __int_as_float(e3.y);
        acc.x += v0.x * w0 + v1.x * w1 + v2.x * w2 + v3.x * w3;
        acc.y += v0.y * w0 + v1.y * w1 + v2.y * w2 + v3.y * w3;
        k += 4;
    }
    while (k < end) {
        const int2 e = csr[k++];
        const float w = __int_as_float(e.y);
        const float2 v = *(const float2*)&hw[(long)e.x * 128 + f];
        acc.x += v.x * w;
        acc.y += v.y * w;
    }

    const float2 b = *(const float2*)&bconv[f];
    float2 o;
    o.x = tanhf(acc.x + b.x);
    o.y = tanhf(acc.y + b.y);
    *(float2*)&hout[node * 128 + f] = o;
}

// ---------------------------------------------------------------------------
// Graph ranges from sorted batch
// ---------------------------------------------------------------------------
__global__ void graph_bounds_k(const int* __restrict__ batch, int* __restrict__ goffs,
                               int N, int G)
{
    int i = blockIdx.x * 256 + threadIdx.x;
    if (i >= N) return;
    int b = batch[i];
    int prev = (i == 0) ? -1 : batch[i - 1];
    for (int g = prev + 1; g <= b; g++) goffs[g] = i;
    if (i == N - 1)
        for (int g = b + 1; g <= G; g++) goffs[g] = N;
}

// ---------------------------------------------------------------------------
// Pool stage 1: parallel partial reduction over node chunks.
// ---------------------------------------------------------------------------
__device__ __forceinline__ unsigned enc_f32(float x)
{
    unsigned u = __float_as_uint(x);
    return (u & 0x80000000u) ? ~u : (u | 0x80000000u);
}
__device__ __forceinline__ float dec_f32(unsigned u)
{
    return (u & 0x80000000u) ? __uint_as_float(u ^ 0x80000000u)
                             : __uint_as_float(~u);
}

#define POOL_CHUNK 32

__global__ __launch_bounds__(128) void pool_partial_k(
    const float* __restrict__ h, const int* __restrict__ batch,
    float* __restrict__ sums, unsigned* __restrict__ maxu, int N)
{
    const int t = threadIdx.x;
    const int lane = t & 31;          // feature group: 4 floats
    const int sub = t >> 5;           // row offset within 4-row sweep
    const int f4 = lane * 4;
    const int i0 = blockIdx.x * POOL_CHUNK;
    const int i1 = min(i0 + POOL_CHUNK, N);

    int cur = -1;
    float4 s = make_float4(0.f, 0.f, 0.f, 0.f);
    float4 m = make_float4(-INFINITY, -INFINITY, -INFINITY, -INFINITY);

#pragma unroll 4
    for (int i = i0 + sub; i < i1; i += 4) {
        const int b = batch[i];
        const float4 v = *(const float4*)&h[(long)i * 128 + f4];
        if (b != cur) {
            if (cur >= 0) {
                atomicAdd(&sums[cur * 128 + f4 + 0], s.x);
                atomicAdd(&sums[cur * 128 + f4 + 1], s.y);
                atomicAdd(&sums[cur * 128 + f4 + 2], s.z);
                atomicAdd(&sums[cur * 128 + f4 + 3], s.w);
                atomicMax(&maxu[cur * 128 + f4 + 0], enc_f32(m.x));
                atomicMax(&maxu[cur * 128 + f4 + 1], enc_f32(m.y));
                atomicMax(&maxu[cur * 128 + f4 + 2], enc_f32(m.z));
                atomicMax(&maxu[cur * 128 + f4 + 3], enc_f32(m.w));
            }
            s = make_float4(0.f, 0.f, 0.f, 0.f);
            m = make_float4(-INFINITY, -INFINITY, -INFINITY, -INFINITY);
            cur = b;
        }
        s.x += v.x; s.y += v.y; s.z += v.z; s.w += v.w;
        m.x = fmaxf(m.x, v.x); m.y = fmaxf(m.y, v.y);
        m.z = fmaxf(m.z, v.z); m.w = fmaxf(m.w, v.w);
    }
    if (cur >= 0) {
        atomicAdd(&sums[cur * 128 + f4 + 0], s.x);
        atomicAdd(&sums[cur * 128 + f4 + 1], s.y);
        atomicAdd(&sums[cur * 128 + f4 + 2], s.z);
        atomicAdd(&sums[cur * 128 + f4 + 3], s.w);
        atomicMax(&maxu[cur * 128 + f4 + 0], enc_f32(m.x));
        atomicMax(&maxu[cur * 128 + f4 + 1], enc_f32(m.y));
        atomicMax(&maxu[cur * 128 + f4 + 2], enc_f32(m.z));
        atomicMax(&maxu[cur * 128 + f4 + 3], enc_f32(m.w));
    }
}

// ---------------------------------------------------------------------------
// Pool stage 2: finalize [sum | max | mean] per graph
// ---------------------------------------------------------------------------
__global__ __launch_bounds__(128) void pool_final_k(
    const float* __restrict__ sums, const unsigned* __restrict__ maxu,
    const int* __restrict__ goffs, float* __restrict__ gout)
{
    const int g = blockIdx.x, f = threadIdx.x;
    const int cnt = goffs[g + 1] - goffs[g];
    const float s = sums[g * 128 + f];
    float mx = (cnt > 0) ? dec_f32(maxu[g * 128 + f]) : 0.0f;
    if (!isfinite(mx)) mx = 0.0f;
    const float mean = s / fmaxf((float)cnt, 1.0f);
    gout[g * 384 + f]       = s;
    gout[g * 384 + 128 + f] = mx;
    gout[g * 384 + 256 + f] = mean;
}

// ---------------------------------------------------------------------------
// MLP head: one block per graph
// ---------------------------------------------------------------------------
__global__ __launch_bounds__(192) void mlp_k(const float* __restrict__ gbuf,
                                             const float* __restrict__ W1,
                                             const float* __restrict__ b1,
                                             const float* __restrict__ W2,
                                             const float* __restrict__ b2,
                                             float* __restrict__ out)
{
    __shared__ float gr[384];
    __shared__ float g1[192];
    const int g = blockIdx.x, t = threadIdx.x;
    for (int i = t; i < 384; i += 192) gr[i] = gbuf[g * 384 + i];
    __syncthreads();
    float acc = b1[t];
    for (int k = 0; k < 384; k++) acc += gr[k] * W1[k * 192 + t];
    acc = acc > 0.f ? acc : 0.01f * acc;
    g1[t] = acc;
    __syncthreads();
    if (t < 10) {
        float a = b2[t];
        for (int k = 0; k < 192; k++) a += g1[k] * W2[k * 10 + t];
        a = a > 0.f ? a : 0.01f * a;
        out[g * 10 + t] = a;
    }
}

// ---------------------------------------------------------------------------
extern "C" void kernel_launch(void* const* d_in, const int* in_sizes, int n_in,
                              void* d_out, int out_size, void* d_ws, size_t ws_size,
                              hipStream_t stream)
{
    const float* x      = (const float*)d_in[0];
    const int*   ei     = (const int*)d_in[1];
    const int*   batch  = (const int*)d_in[2];
    const float* W_emb  = (const float*)d_in[3];
    const float* b_emb  = (const float*)d_in[4];
    const float* W_conv = (const float*)d_in[5];
    const float* b_conv = (const float*)d_in[6];
    const float* W1     = (const float*)d_in[7];
    const float* b1     = (const float*)d_in[8];
    const float* W2     = (const float*)d_in[9];
    const float* b2     = (const float*)d_in[10];
    float* out = (float*)d_out;

    const int N  = in_sizes[2];          // 100000
    const int E  = in_sizes[1] / 2;      // 1600000
    const int G  = 128;
    const int NL = 5;
    const int HID = 128;

    const int* e_src = ei;
    const int* e_dst = ei + E;

    // workspace carve-up
    char* ws = (char*)d_ws;
    size_t off = 0;
    auto alloc = [&](size_t bytes) -> void* {
        void* p = ws + off;
        off += (bytes + 255) & ~(size_t)255;
        return p;
    };
    float*    hbuf     = (float*)   alloc((size_t)N * HID * 4);
    float*    hwbuf    = (float*)   alloc((size_t)N * HID * 4);
    float*    dinv     = (float*)   alloc((size_t)N * 4);
    int*      cnt      = (int*)     alloc((size_t)N * 4);
    int*      offs     = (int*)     alloc((size_t)(N + 1) * 4);
    int*      bsums    = (int*)     alloc(512 * 4);
    int2*     csr      = (int2*)    alloc((size_t)E * 8);
    int*      goffs    = (int*)     alloc((size_t)(G + 1) * 4);
    float*    gbuf     = (float*)   alloc((size_t)G * 384 * 4);
    float*    psums    = (float*)   alloc((size_t)G * 128 * 4);
    unsigned* pmaxu    = (unsigned*)alloc((size_t)G * 128 * 4);

    const int nb_nodes = (N + 255) / 256;
    const int nb_edges = (E + 255) / 256;

    // 1) degree + dinv
    (void)hipMemsetAsync(cnt, 0, (size_t)N * 4, stream);
    count_edges_k<<<nb_edges, 256, 0, stream>>>(e_dst, cnt, E);
    dinv_k<<<nb_nodes, 256, 0, stream>>>(cnt, dinv, N);

    // 2) CSR offsets (exclusive scan of cnt)
    scan_block_k<<<nb_nodes, 256, 0, stream>>>(cnt, offs, bsums, N);
    scan_tops_k<<<1, 512, 0, stream>>>(bsums, nb_nodes);
    scan_add_k<<<nb_nodes, 256, 0, stream>>>(offs, bsums, N, E);

    // 3) CSR fill
    (void)hipMemsetAsync(cnt, 0, (size_t)N * 4, stream);
    fill_csr_k<<<nb_edges, 256, 0, stream>>>(e_src, e_dst, offs, cnt, dinv, csr, E);

    // 4) input embedding: h = x @ W_emb + b_emb
    dense_k<64, true><<<(N + 127) / 128, 256, 0, stream>>>(x, W_emb, b_emb, hbuf, N);

    // 5) GCN layers
    for (int l = 0; l < NL; l++) {
        dense_k<128, false><<<(N + 127) / 128, 256, 0, stream>>>(
            hbuf, W_conv + (size_t)l * HID * HID, nullptr, hwbuf, N);
        aggregate_k<<<(N + 3) / 4, 256, 0, stream>>>(
            hwbuf, offs, csr, dinv, b_conv + (size_t)l * HID, hbuf, N);
    }

    // 6) pooling (parallel two-stage)
    graph_bounds_k<<<nb_nodes, 256, 0, stream>>>(batch, goffs, N, G);
    (void)hipMemsetAsync(psums, 0, (size_t)G * 128 * 4, stream);
    (void)hipMemsetAsync(pmaxu, 0, (size_t)G * 128 * 4, stream);
    pool_partial_k<<<(N + POOL_CHUNK - 1) / POOL_CHUNK, 128, 0, stream>>>(
        hbuf, batch, psums, pmaxu, N);
    pool_final_k<<<G, 128, 0, stream>>>(psums, pmaxu, goffs, gbuf);

    // 7) MLP head
    mlp_k<<<G, 192, 0, stream>>>(gbuf, W1, b1, W2, b2, out);
}

// Round 7
// 916.223 us; speedup vs baseline: 1.5167x; 1.2372x over previous
//
#include <hip/hip_runtime.h>
#include <hip/hip_fp16.h>
#include <math.h>

// ---------------------------------------------------------------------------
// Dense v2: out[M,128] = A[M,K] @ W[K,128] (+ bias).
// 128x128 block tile, BK=32 k-chunks, A and W staged in LDS, 8x8 micro-tile.
// OUT_HALF: emit fp16 (for the aggregation gather path).
// ---------------------------------------------------------------------------
template<int K, bool HAS_BIAS, bool OUT_HALF>
__global__ __launch_bounds__(256) void dense_k(
    const float* __restrict__ A, const float* __restrict__ W,
    const float* __restrict__ bias, void* __restrict__ out_, int M)
{
    constexpr int BK = 32;
    __shared__ float As[128 * BK];   // row-major [128][BK]
    __shared__ float Ws[BK * 128];   // row-major [BK][128]

    const int t  = threadIdx.x;
    const int tx = t & 15, ty = t >> 4;
    const int c0 = tx * 8;
    const int r0 = ty * 8;
    const long row0 = (long)blockIdx.x * 128;

    float acc[8][8] = {{0.f}};

    for (int k0 = 0; k0 < K; k0 += BK) {
#pragma unroll
        for (int it = 0; it < 4; it++) {
            const int f  = t + it * 256;      // float4 index 0..1023
            const int r  = f >> 3;            // 8 float4 per row
            const int kq = f & 7;
            long gr = row0 + r; if (gr > (long)M - 1) gr = (long)M - 1;
            *(float4*)&As[r * BK + kq * 4] =
                *(const float4*)&A[gr * K + k0 + kq * 4];
        }
#pragma unroll
        for (int it = 0; it < 4; it++) {
            const int f = t + it * 256;
            *(float4*)&Ws[f * 4] = *(const float4*)&W[(long)k0 * 128 + f * 4];
        }
        __syncthreads();

#pragma unroll
        for (int kq = 0; kq < BK / 4; kq++) {
            float4 a[8];
#pragma unroll
            for (int i = 0; i < 8; i++)
                a[i] = *(const float4*)&As[(r0 + i) * BK + kq * 4];
#pragma unroll
            for (int kk = 0; kk < 4; kk++) {
                const int k = kq * 4 + kk;
                const float4 w0 = *(const float4*)&Ws[k * 128 + c0];
                const float4 w1 = *(const float4*)&Ws[k * 128 + c0 + 4];
#pragma unroll
                for (int i = 0; i < 8; i++) {
                    const float av = (kk == 0) ? a[i].x : (kk == 1) ? a[i].y
                                   : (kk == 2) ? a[i].z : a[i].w;
                    acc[i][0] += av * w0.x; acc[i][1] += av * w0.y;
                    acc[i][2] += av * w0.z; acc[i][3] += av * w0.w;
                    acc[i][4] += av * w1.x; acc[i][5] += av * w1.y;
                    acc[i][6] += av * w1.z; acc[i][7] += av * w1.w;
                }
            }
        }
        __syncthreads();
    }

    float bv[8] = {0.f};
    if (HAS_BIAS) {
#pragma unroll
        for (int j = 0; j < 8; j++) bv[j] = bias[c0 + j];
    }
#pragma unroll
    for (int i = 0; i < 8; i++) {
        const long gr = row0 + r0 + i;
        if (gr < M) {
            if constexpr (OUT_HALF) {
                alignas(16) __half h8[8];
#pragma unroll
                for (int j = 0; j < 8; j++)
                    h8[j] = __float2half(acc[i][j] + bv[j]);
                *(float4*)&((__half*)out_)[gr * 128 + c0] = *(float4*)h8;
            } else {
                alignas(16) float f8[8];
#pragma unroll
                for (int j = 0; j < 8; j++) f8[j] = acc[i][j] + bv[j];
                *(float4*)&((float*)out_)[gr * 128 + c0]     = *(float4*)&f8[0];
                *(float4*)&((float*)out_)[gr * 128 + c0 + 4] = *(float4*)&f8[4];
            }
        }
    }
}

// ---------------------------------------------------------------------------
// Degree count (real edges only; self-loop added analytically later)
// ---------------------------------------------------------------------------
__global__ void count_edges_k(const int* __restrict__ dst, int* __restrict__ cnt, int E)
{
    int e = blockIdx.x * 256 + threadIdx.x;
    if (e < E) atomicAdd(&cnt[dst[e]], 1);
}

__global__ void dinv_k(const int* __restrict__ cnt, float* __restrict__ dinv, int N)
{
    int i = blockIdx.x * 256 + threadIdx.x;
    if (i < N) dinv[i] = rsqrtf((float)cnt[i] + 1.0f);   // +1 = self loop
}

// ---------------------------------------------------------------------------
// 3-kernel exclusive prefix scan over cnt -> offs
// ---------------------------------------------------------------------------
__global__ void scan_block_k(const int* __restrict__ cnt, int* __restrict__ offs,
                             int* __restrict__ bsums, int N)
{
    __shared__ int tmp[256];
    int i = blockIdx.x * 256 + threadIdx.x;
    int v = (i < N) ? cnt[i] : 0;
    tmp[threadIdx.x] = v;
    __syncthreads();
    for (int off = 1; off < 256; off <<= 1) {
        int add = (threadIdx.x >= off) ? tmp[threadIdx.x - off] : 0;
        __syncthreads();
        tmp[threadIdx.x] += add;
        __syncthreads();
    }
    if (i < N) offs[i] = tmp[threadIdx.x] - v;           // exclusive within block
    if (threadIdx.x == 255) bsums[blockIdx.x] = tmp[255];
}

__global__ void scan_tops_k(int* __restrict__ bsums, int nb)
{
    __shared__ int tmp[512];
    int t = threadIdx.x;
    int v = (t < nb) ? bsums[t] : 0;
    tmp[t] = v;
    __syncthreads();
    for (int off = 1; off < 512; off <<= 1) {
        int add = (t >= off) ? tmp[t - off] : 0;
        __syncthreads();
        tmp[t] += add;
        __syncthreads();
    }
    if (t < nb) bsums[t] = tmp[t] - v;                   // exclusive over blocks
}

__global__ void scan_add_k(int* __restrict__ offs, const int* __restrict__ bsums,
                           int N, int E)
{
    int i = blockIdx.x * 256 + threadIdx.x;
    if (i < N) offs[i] += bsums[blockIdx.x];
    if (i == 0) offs[N] = E;
}

// ---------------------------------------------------------------------------
// CSR fill: interleaved (src, norm) pairs grouped by dst
// ---------------------------------------------------------------------------
__global__ void fill_csr_k(const int* __restrict__ src, const int* __restrict__ dst,
                           const int* __restrict__ offs, int* __restrict__ fillc,
                           const float* __restrict__ dinv,
                           int2* __restrict__ csr, int E)
{
    int e = blockIdx.x * 256 + threadIdx.x;
    if (e >= E) return;
    int s = src[e], d = dst[e];
    int slot = offs[d] + atomicAdd(&fillc[d], 1);
    int2 p;
    p.x = s;
    p.y = __float_as_int(dinv[s] * dinv[d]);
    csr[slot] = p;
}

// ---------------------------------------------------------------------------
// Aggregation: one wave per node, lane = 2 features (one __half2 = 4B).
// hw is fp16: 256B per row-gather. 4 independent gathers in flight per wave.
// Accumulation in fp32; output h stays fp32.
// ---------------------------------------------------------------------------
__global__ __launch_bounds__(256) void aggregate_k(
    const __half2* __restrict__ hw2, const int* __restrict__ offs,
    const int2* __restrict__ csr, const float* __restrict__ dinv,
    const float* __restrict__ bconv, float* __restrict__ hout, int N)
{
    const int wid = threadIdx.x >> 6;
    const int lane = threadIdx.x & 63;
    const long node = (long)blockIdx.x * 4 + wid;
    if (node >= N) return;

    const float di = dinv[node];
    const float2 self = __half22float2(hw2[node * 64 + lane]);
    float2 acc;
    acc.x = self.x * di * di;
    acc.y = self.y * di * di;

    int k = offs[node];
    const int end = offs[node + 1];

    while (k + 4 <= end) {
        const int2 e0 = csr[k + 0];
        const int2 e1 = csr[k + 1];
        const int2 e2 = csr[k + 2];
        const int2 e3 = csr[k + 3];
        const __half2 p0 = hw2[(long)e0.x * 64 + lane];
        const __half2 p1 = hw2[(long)e1.x * 64 + lane];
        const __half2 p2 = hw2[(long)e2.x * 64 + lane];
        const __half2 p3 = hw2[(long)e3.x * 64 + lane];
        const float w0 = __int_as_float(e0.y);
        const float w1 = __int_as_float(e1.y);
        const float w2 = __int_as_float(e2.y);
        const float w3 = __int_as_float(e3.y);
        const float2 v0 = __half22float2(p0);
        const float2 v1 = __half22float2(p1);
        const float2 v2 = __half22float2(p2);
        const float2 v3 = __half22float2(p3);
        acc.x += v0.x * w0 + v1.x * w1 + v2.x * w2 + v3.x * w3;
        acc.y += v0.y * w0 + v1.y * w1 + v2.y * w2 + v3.y * w3;
        k += 4;
    }
    while (k < end) {
        const int2 e = csr[k++];
        const float w = __int_as_float(e.y);
        const float2 v = __half22float2(hw2[(long)e.x * 64 + lane]);
        acc.x += v.x * w;
        acc.y += v.y * w;
    }

    const int f = lane * 2;
    const float2 b = *(const float2*)&bconv[f];
    float2 o;
    o.x = tanhf(acc.x + b.x);
    o.y = tanhf(acc.y + b.y);
    *(float2*)&hout[node * 128 + f] = o;
}

// ---------------------------------------------------------------------------
// Graph ranges from sorted batch
// ---------------------------------------------------------------------------
__global__ void graph_bounds_k(const int* __restrict__ batch, int* __restrict__ goffs,
                               int N, int G)
{
    int i = blockIdx.x * 256 + threadIdx.x;
    if (i >= N) return;
    int b = batch[i];
    int prev = (i == 0) ? -1 : batch[i - 1];
    for (int g = prev + 1; g <= b; g++) goffs[g] = i;
    if (i == N - 1)
        for (int g = b + 1; g <= G; g++) goffs[g] = N;
}

// ---------------------------------------------------------------------------
// Pool stage 1: parallel partial reduction over node chunks.
// ---------------------------------------------------------------------------
__device__ __forceinline__ unsigned enc_f32(float x)
{
    unsigned u = __float_as_uint(x);
    return (u & 0x80000000u) ? ~u : (u | 0x80000000u);
}
__device__ __forceinline__ float dec_f32(unsigned u)
{
    return (u & 0x80000000u) ? __uint_as_float(u ^ 0x80000000u)
                             : __uint_as_float(~u);
}

#define POOL_CHUNK 32

__global__ __launch_bounds__(128) void pool_partial_k(
    const float* __restrict__ h, const int* __restrict__ batch,
    float* __restrict__ sums, unsigned* __restrict__ maxu, int N)
{
    const int t = threadIdx.x;
    const int lane = t & 31;          // feature group: 4 floats
    const int sub = t >> 5;           // row offset within 4-row sweep
    const int f4 = lane * 4;
    const int i0 = blockIdx.x * POOL_CHUNK;
    const int i1 = min(i0 + POOL_CHUNK, N);

    int cur = -1;
    float4 s = make_float4(0.f, 0.f, 0.f, 0.f);
    float4 m = make_float4(-INFINITY, -INFINITY, -INFINITY, -INFINITY);

#pragma unroll 4
    for (int i = i0 + sub; i < i1; i += 4) {
        const int b = batch[i];
        const float4 v = *(const float4*)&h[(long)i * 128 + f4];
        if (b != cur) {
            if (cur >= 0) {
                atomicAdd(&sums[cur * 128 + f4 + 0], s.x);
                atomicAdd(&sums[cur * 128 + f4 + 1], s.y);
                atomicAdd(&sums[cur * 128 + f4 + 2], s.z);
                atomicAdd(&sums[cur * 128 + f4 + 3], s.w);
                atomicMax(&maxu[cur * 128 + f4 + 0], enc_f32(m.x));
                atomicMax(&maxu[cur * 128 + f4 + 1], enc_f32(m.y));
                atomicMax(&maxu[cur * 128 + f4 + 2], enc_f32(m.z));
                atomicMax(&maxu[cur * 128 + f4 + 3], enc_f32(m.w));
            }
            s = make_float4(0.f, 0.f, 0.f, 0.f);
            m = make_float4(-INFINITY, -INFINITY, -INFINITY, -INFINITY);
            cur = b;
        }
        s.x += v.x; s.y += v.y; s.z += v.z; s.w += v.w;
        m.x = fmaxf(m.x, v.x); m.y = fmaxf(m.y, v.y);
        m.z = fmaxf(m.z, v.z); m.w = fmaxf(m.w, v.w);
    }
    if (cur >= 0) {
        atomicAdd(&sums[cur * 128 + f4 + 0], s.x);
        atomicAdd(&sums[cur * 128 + f4 + 1], s.y);
        atomicAdd(&sums[cur * 128 + f4 + 2], s.z);
        atomicAdd(&sums[cur * 128 + f4 + 3], s.w);
        atomicMax(&maxu[cur * 128 + f4 + 0], enc_f32(m.x));
        atomicMax(&maxu[cur * 128 + f4 + 1], enc_f32(m.y));
        atomicMax(&maxu[cur * 128 + f4 + 2], enc_f32(m.z));
        atomicMax(&maxu[cur * 128 + f4 + 3], enc_f32(m.w));
    }
}

// ---------------------------------------------------------------------------
// Pool stage 2: finalize [sum | max | mean] per graph
// ---------------------------------------------------------------------------
__global__ __launch_bounds__(128) void pool_final_k(
    const float* __restrict__ sums, const unsigned* __restrict__ maxu,
    const int* __restrict__ goffs, float* __restrict__ gout)
{
    const int g = blockIdx.x, f = threadIdx.x;
    const int cnt = goffs[g + 1] - goffs[g];
    const float s = sums[g * 128 + f];
    float mx = (cnt > 0) ? dec_f32(maxu[g * 128 + f]) : 0.0f;
    if (!isfinite(mx)) mx = 0.0f;
    const float mean = s / fmaxf((float)cnt, 1.0f);
    gout[g * 384 + f]       = s;
    gout[g * 384 + 128 + f] = mx;
    gout[g * 384 + 256 + f] = mean;
}

// ---------------------------------------------------------------------------
// MLP head: one block per graph
// ---------------------------------------------------------------------------
__global__ __launch_bounds__(192) void mlp_k(const float* __restrict__ gbuf,
                                             const float* __restrict__ W1,
                                             const float* __restrict__ b1,
                                             const float* __restrict__ W2,
                                             const float* __restrict__ b2,
                                             float* __restrict__ out)
{
    __shared__ float gr[384];
    __shared__ float g1[192];
    const int g = blockIdx.x, t = threadIdx.x;
    for (int i = t; i < 384; i += 192) gr[i] = gbuf[g * 384 + i];
    __syncthreads();
    float acc = b1[t];
    for (int k = 0; k < 384; k++) acc += gr[k] * W1[k * 192 + t];
    acc = acc > 0.f ? acc : 0.01f * acc;
    g1[t] = acc;
    __syncthreads();
    if (t < 10) {
        float a = b2[t];
        for (int k = 0; k < 192; k++) a += g1[k] * W2[k * 10 + t];
        a = a > 0.f ? a : 0.01f * a;
        out[g * 10 + t] = a;
    }
}

// ---------------------------------------------------------------------------
extern "C" void kernel_launch(void* const* d_in, const int* in_sizes, int n_in,
                              void* d_out, int out_size, void* d_ws, size_t ws_size,
                              hipStream_t stream)
{
    const float* x      = (const float*)d_in[0];
    const int*   ei     = (const int*)d_in[1];
    const int*   batch  = (const int*)d_in[2];
    const float* W_emb  = (const float*)d_in[3];
    const float* b_emb  = (const float*)d_in[4];
    const float* W_conv = (const float*)d_in[5];
    const float* b_conv = (const float*)d_in[6];
    const float* W1     = (const float*)d_in[7];
    const float* b1     = (const float*)d_in[8];
    const float* W2     = (const float*)d_in[9];
    const float* b2     = (const float*)d_in[10];
    float* out = (float*)d_out;

    const int N  = in_sizes[2];          // 100000
    const int E  = in_sizes[1] / 2;      // 1600000
    const int G  = 128;
    const int NL = 5;
    const int HID = 128;

    const int* e_src = ei;
    const int* e_dst = ei + E;

    // workspace carve-up
    char* ws = (char*)d_ws;
    size_t off = 0;
    auto alloc = [&](size_t bytes) -> void* {
        void* p = ws + off;
        off += (bytes + 255) & ~(size_t)255;
        return p;
    };
    float*    hbuf     = (float*)   alloc((size_t)N * HID * 4);
    __half*   hwbuf    = (__half*)  alloc((size_t)N * HID * 2);
    float*    dinv     = (float*)   alloc((size_t)N * 4);
    int*      cnt      = (int*)     alloc((size_t)N * 4);
    int*      offs     = (int*)     alloc((size_t)(N + 1) * 4);
    int*      bsums    = (int*)     alloc(512 * 4);
    int2*     csr      = (int2*)    alloc((size_t)E * 8);
    int*      goffs    = (int*)     alloc((size_t)(G + 1) * 4);
    float*    gbuf     = (float*)   alloc((size_t)G * 384 * 4);
    float*    psums    = (float*)   alloc((size_t)G * 128 * 4);
    unsigned* pmaxu    = (unsigned*)alloc((size_t)G * 128 * 4);

    const int nb_nodes = (N + 255) / 256;
    const int nb_edges = (E + 255) / 256;

    // 1) degree + dinv
    (void)hipMemsetAsync(cnt, 0, (size_t)N * 4, stream);
    count_edges_k<<<nb_edges, 256, 0, stream>>>(e_dst, cnt, E);
    dinv_k<<<nb_nodes, 256, 0, stream>>>(cnt, dinv, N);

    // 2) CSR offsets (exclusive scan of cnt)
    scan_block_k<<<nb_nodes, 256, 0, stream>>>(cnt, offs, bsums, N);
    scan_tops_k<<<1, 512, 0, stream>>>(bsums, nb_nodes);
    scan_add_k<<<nb_nodes, 256, 0, stream>>>(offs, bsums, N, E);

    // 3) CSR fill
    (void)hipMemsetAsync(cnt, 0, (size_t)N * 4, stream);
    fill_csr_k<<<nb_edges, 256, 0, stream>>>(e_src, e_dst, offs, cnt, dinv, csr, E);

    // 4) input embedding: h = x @ W_emb + b_emb  (fp32 out)
    dense_k<64, true, false><<<(N + 127) / 128, 256, 0, stream>>>(
        x, W_emb, b_emb, hbuf, N);

    // 5) GCN layers: dense emits fp16 hw; aggregate gathers fp16, accum fp32
    for (int l = 0; l < NL; l++) {
        dense_k<128, false, true><<<(N + 127) / 128, 256, 0, stream>>>(
            hbuf, W_conv + (size_t)l * HID * HID, nullptr, hwbuf, N);
        aggregate_k<<<(N + 3) / 4, 256, 0, stream>>>(
            (const __half2*)hwbuf, offs, csr, dinv,
            b_conv + (size_t)l * HID, hbuf, N);
    }

    // 6) pooling (parallel two-stage)
    graph_bounds_k<<<nb_nodes, 256, 0, stream>>>(batch, goffs, N, G);
    (void)hipMemsetAsync(psums, 0, (size_t)G * 128 * 4, stream);
    (void)hipMemsetAsync(pmaxu, 0, (size_t)G * 128 * 4, stream);
    pool_partial_k<<<(N + POOL_CHUNK - 1) / POOL_CHUNK, 128, 0, stream>>>(
        hbuf, batch, psums, pmaxu, N);
    pool_final_k<<<G, 128, 0, stream>>>(psums, pmaxu, goffs, gbuf);

    // 7) MLP head
    mlp_k<<<G, 192, 0, stream>>>(gbuf, W1, b1, W2, b2, out);
}